// Round 1
// baseline (2147.674 us; speedup 1.0000x reference)
//
#include <hip/hip_runtime.h>

// GCN: N=50000 nodes, E=800000 edges, 64 -> 96 -> 96 -> 32, fp32.
// Decomposition: dinv = rsqrt(1 + indeg);  per layer:
//   hn = (x @ W) * dinv[n]          (GEMM epilogue, written to A and B)
//   t[d] = hn[d] + sum_{s->d} hn[s] (B initialized by GEMM, edges atomic-add)
//   h' = relu(dinv[n] * t[n] + b)   (fused into next GEMM's tile load)

constexpr int NN = 50000;
constexpr int NE = 800000;
constexpr int IN_C = 64, HID_C = 96, OUT_C = 32;

__global__ void init_deg(float* deg) {
  int i = blockIdx.x * blockDim.x + threadIdx.x;
  if (i < NN) deg[i] = 1.0f;  // self-loop
}

__global__ void deg_accum(const int* __restrict__ ei, float* deg) {
  int i = blockIdx.x * blockDim.x + threadIdx.x;
  if (i < NE) unsafeAtomicAdd(&deg[ei[NE + i]], 1.0f);
}

__global__ void deg_rsqrt(float* deg) {
  int i = blockIdx.x * blockDim.x + threadIdx.x;
  if (i < NN) deg[i] = rsqrtf(deg[i]);
}

// B[dst] += A[src], 96 channels per edge, 4 channels (float4 load) per thread.
__global__ void scatter_add(const int* __restrict__ ei,
                            const float* __restrict__ A,
                            float* __restrict__ B) {
  constexpr int QP = HID_C / 4;  // 24
  int gid = blockIdx.x * blockDim.x + threadIdx.x;
  if (gid >= NE * QP) return;
  int e = gid / QP;
  int q = gid - e * QP;
  int s = ei[e];
  int d = ei[NE + e];
  float4 v = *(const float4*)(A + (size_t)s * HID_C + 4 * q);
  float* bp = B + (size_t)d * HID_C + 4 * q;
  unsafeAtomicAdd(bp + 0, v.x);
  unsafeAtomicAdd(bp + 1, v.y);
  unsafeAtomicAdd(bp + 2, v.z);
  unsafeAtomicAdd(bp + 3, v.w);
}

// MODE 0: in = raw X;                     epilogue: v = acc*dinv -> outA, outB
// MODE 1: in = relu(dinv*X + bin);        epilogue: v = acc*dinv -> outA, outB
// MODE 2: in = relu(dinv*X + bin);        epilogue: v = acc + bout -> outA
template <int K, int M, int BN, int NPT, int CPT, int MODE, int BLOCK>
__global__ __launch_bounds__(BLOCK) void gcn_gemm(
    const float* __restrict__ X, const float* __restrict__ W,
    const float* __restrict__ bin, const float* __restrict__ dinv,
    float* __restrict__ outA, float* __restrict__ outB,
    const float* __restrict__ bout) {
  constexpr int TCX = M / CPT;
  constexpr int TRY = BN / NPT;
  static_assert(TCX * TRY == BLOCK, "thread layout mismatch");
  __shared__ float sW[K * M];
  __shared__ float sX[BN][K + 1];

  const int tid = threadIdx.x;
  const int nb = blockIdx.x * BN;

  {  // load W (KxM, row-major) via float4
    const float4* W4 = (const float4*)W;
    float4* sW4 = (float4*)sW;
    #pragma unroll
    for (int i = tid; i < K * M / 4; i += BLOCK) sW4[i] = W4[i];
  }
  {  // load X tile [BN][K], fused input transform for MODE 1/2
    constexpr int KQ = K / 4;
    for (int i = tid; i < BN * KQ; i += BLOCK) {
      int n = i / KQ, kq = i - n * KQ;
      int gn = nb + n;
      float4 v = {0.f, 0.f, 0.f, 0.f};
      if (gn < NN) {
        v = *(const float4*)(X + (size_t)gn * K + 4 * kq);
        if (MODE != 0) {
          float di = dinv[gn];
          v.x = fmaxf(fmaf(di, v.x, bin[4 * kq + 0]), 0.f);
          v.y = fmaxf(fmaf(di, v.y, bin[4 * kq + 1]), 0.f);
          v.z = fmaxf(fmaf(di, v.z, bin[4 * kq + 2]), 0.f);
          v.w = fmaxf(fmaf(di, v.w, bin[4 * kq + 3]), 0.f);
        }
      }
      sX[n][4 * kq + 0] = v.x;
      sX[n][4 * kq + 1] = v.y;
      sX[n][4 * kq + 2] = v.z;
      sX[n][4 * kq + 3] = v.w;
    }
  }
  __syncthreads();

  const int cx = tid % TCX, ry = tid / TCX;
  const int c0 = cx * CPT, r0 = ry * NPT;
  float acc[NPT][CPT] = {};
  #pragma unroll 4
  for (int k = 0; k < K; ++k) {
    float wv[CPT], xv[NPT];
    #pragma unroll
    for (int j = 0; j < CPT; ++j) wv[j] = sW[k * M + c0 + j];
    #pragma unroll
    for (int i = 0; i < NPT; ++i) xv[i] = sX[r0 + i][k];
    #pragma unroll
    for (int i = 0; i < NPT; ++i)
      #pragma unroll
      for (int j = 0; j < CPT; ++j) acc[i][j] = fmaf(xv[i], wv[j], acc[i][j]);
  }

  #pragma unroll
  for (int i = 0; i < NPT; ++i) {
    int gn = nb + r0 + i;
    if (gn >= NN) continue;
    if (MODE == 2) {
      #pragma unroll
      for (int j = 0; j < CPT; ++j)
        outA[(size_t)gn * M + c0 + j] = acc[i][j] + bout[c0 + j];
    } else {
      float di = dinv[gn];
      #pragma unroll
      for (int j = 0; j < CPT; ++j) {
        float v = acc[i][j] * di;
        outA[(size_t)gn * M + c0 + j] = v;
        outB[(size_t)gn * M + c0 + j] = v;  // self-loop init for scatter
      }
    }
  }
}

extern "C" void kernel_launch(void* const* d_in, const int* in_sizes, int n_in,
                              void* d_out, int out_size, void* d_ws,
                              size_t ws_size, hipStream_t stream) {
  const float* x   = (const float*)d_in[0];
  const int*   ei  = (const int*)d_in[1];
  const float* W1  = (const float*)d_in[2];
  const float* b1  = (const float*)d_in[3];
  const float* W2  = (const float*)d_in[4];
  const float* b2  = (const float*)d_in[5];
  const float* Wfc = (const float*)d_in[6];
  const float* bfc = (const float*)d_in[7];
  float* out = (float*)d_out;

  float* dinv = (float*)d_ws;
  float* A = dinv + 50048;                    // hn buffer [N][96]
  float* B = A + (size_t)NN * HID_C;          // t  buffer [N][96]

  init_deg<<<(NN + 255) / 256, 256, 0, stream>>>(dinv);
  deg_accum<<<(NE + 255) / 256, 256, 0, stream>>>(ei, dinv);
  deg_rsqrt<<<(NN + 255) / 256, 256, 0, stream>>>(dinv);

  // Layer 1: A = B = (x @ W1) * dinv
  gcn_gemm<64, 96, 64, 8, 6, 0, 128>
      <<<(NN + 63) / 64, 128, 0, stream>>>(x, W1, nullptr, dinv, A, B, nullptr);
  scatter_add<<<(NE * 24 + 255) / 256, 256, 0, stream>>>(ei, A, B);

  // Layer 2: reads B with relu(dinv*B + b1) transform; A = B = (h1 @ W2)*dinv
  gcn_gemm<96, 96, 64, 8, 6, 1, 128>
      <<<(NN + 63) / 64, 128, 0, stream>>>(B, W2, b1, dinv, A, B, nullptr);
  scatter_add<<<(NE * 24 + 255) / 256, 256, 0, stream>>>(ei, A, B);

  // FC: out = relu(dinv*B + b2) @ Wfc + bfc
  gcn_gemm<96, 32, 128, 8, 4, 2, 128>
      <<<(NN + 127) / 128, 128, 0, stream>>>(B, Wfc, b2, dinv, out, nullptr, bfc);
}

// Round 2
// 291.556 us; speedup vs baseline: 7.3663x; 7.3663x over previous
//
#include <hip/hip_runtime.h>

// GCN: N=50000 nodes, E=800000 edges, 64 -> 96 -> 96 -> 32, fp32.
// R1: replace fp32 scatter-atomics (2x1002us) with CSR-by-dst counting sort +
// pull-style gather (no float atomics, coalesced writes, L2/LLC-resident reads).
//   counts = in-degree histogram  -> dinv = rsqrt(1+counts)
//   row_start = exclusive_scan(counts); srcs = edges sorted by dst
//   per layer: A = (in @ W) * dinv          (GEMM epilogue)
//              B[n] = A[n] + sum_{s->n} A[s] (gather, no atomics)
//              next input = relu(dinv*B + b) (fused into next GEMM tile load)

constexpr int NN = 50000;
constexpr int NE = 800000;
constexpr int HID_C = 96;
constexpr int NCHUNK = (NN + 255) / 256;  // 196

// ---------------- CSR build (counting sort by dst) ----------------

__global__ void hist_zero(int* counts) {
  int i = blockIdx.x * blockDim.x + threadIdx.x;
  if (i < NN) counts[i] = 0;
}

__global__ void hist(const int* __restrict__ ei, int* counts) {
  int i = blockIdx.x * blockDim.x + threadIdx.x;
  if (i < NE) atomicAdd(&counts[ei[NE + i]], 1);
}

__global__ void scan_reduce(const int* __restrict__ counts, int* partials) {
  __shared__ int s[256];
  int t = threadIdx.x, i = blockIdx.x * 256 + t;
  s[t] = (i < NN) ? counts[i] : 0;
  __syncthreads();
  for (int off = 128; off > 0; off >>= 1) {
    if (t < off) s[t] += s[t + off];
    __syncthreads();
  }
  if (t == 0) partials[blockIdx.x] = s[0];
}

__global__ void scan_partials(int* partials) {  // 1 block, NCHUNK <= 256
  __shared__ int s[256];
  int t = threadIdx.x;
  int v = (t < NCHUNK) ? partials[t] : 0;
  s[t] = v;
  __syncthreads();
  for (int off = 1; off < 256; off <<= 1) {
    int add = (t >= off) ? s[t - off] : 0;
    __syncthreads();
    s[t] += add;
    __syncthreads();
  }
  if (t < NCHUNK) partials[t] = s[t] - v;  // exclusive
}

__global__ void scan_finalize(const int* __restrict__ counts,
                              const int* __restrict__ partials, int* row_start,
                              int* cursor, float* dinv) {
  __shared__ int s[256];
  int t = threadIdx.x, i = blockIdx.x * 256 + t;
  int v = (i < NN) ? counts[i] : 0;
  s[t] = v;
  __syncthreads();
  for (int off = 1; off < 256; off <<= 1) {
    int add = (t >= off) ? s[t - off] : 0;
    __syncthreads();
    s[t] += add;
    __syncthreads();
  }
  if (i < NN) {
    int start = partials[blockIdx.x] + s[t] - v;  // exclusive within chunk
    row_start[i] = start;
    cursor[i] = start;
    dinv[i] = rsqrtf(1.0f + (float)v);
  }
}

__global__ void fill_csr(const int* __restrict__ ei, int* cursor,
                         int* __restrict__ srcs) {
  int e = blockIdx.x * blockDim.x + threadIdx.x;
  if (e < NE) {
    int d = ei[NE + e];
    int p = atomicAdd(&cursor[d], 1);
    srcs[p] = ei[e];
  }
}

// ---------------- gather: B[n] = A[n] + sum_{s in srcs(n)} A[s] -------------
// thread = (node n, float4-quad q of 24); 24 consecutive lanes cover one row.
__global__ void gather(const int* __restrict__ row_start,
                       const int* __restrict__ counts,
                       const int* __restrict__ srcs,
                       const float* __restrict__ A, float* __restrict__ B) {
  constexpr int QP = HID_C / 4;  // 24
  int gid = blockIdx.x * blockDim.x + threadIdx.x;
  if (gid >= NN * QP) return;
  int n = gid / QP;
  int q = gid - n * QP;
  const float4* A4 = (const float4*)A;
  float4 acc = A4[(size_t)n * QP + q];  // self-loop term
  int s0 = row_start[n];
  int cnt = counts[n];
  for (int p = 0; p < cnt; ++p) {
    int s = srcs[s0 + p];  // broadcast across the 24 lanes of this node
    float4 v = A4[(size_t)s * QP + q];
    acc.x += v.x; acc.y += v.y; acc.z += v.z; acc.w += v.w;
  }
  ((float4*)B)[(size_t)n * QP + q] = acc;
}

// ---------------- GEMM with fused transforms ----------------
// MODE 0: in = raw X;              epilogue: v = acc*dinv -> outA
// MODE 1: in = relu(dinv*X + bin); epilogue: v = acc*dinv -> outA
// MODE 2: in = relu(dinv*X + bin); epilogue: v = acc + bout -> outA
template <int K, int M, int BN, int NPT, int CPT, int MODE, int BLOCK>
__global__ __launch_bounds__(BLOCK) void gcn_gemm(
    const float* __restrict__ X, const float* __restrict__ W,
    const float* __restrict__ bin, const float* __restrict__ dinv,
    float* __restrict__ outA, const float* __restrict__ bout) {
  constexpr int TCX = M / CPT;
  constexpr int TRY = BN / NPT;
  static_assert(TCX * TRY == BLOCK, "thread layout mismatch");
  __shared__ float sW[K * M];
  __shared__ float sX[BN][K + 1];

  const int tid = threadIdx.x;
  const int nb = blockIdx.x * BN;

  {  // load W (KxM, row-major) via float4
    const float4* W4 = (const float4*)W;
    float4* sW4 = (float4*)sW;
    #pragma unroll
    for (int i = tid; i < K * M / 4; i += BLOCK) sW4[i] = W4[i];
  }
  {  // load X tile [BN][K], fused input transform for MODE 1/2
    constexpr int KQ = K / 4;
    for (int i = tid; i < BN * KQ; i += BLOCK) {
      int n = i / KQ, kq = i - n * KQ;
      int gn = nb + n;
      float4 v = {0.f, 0.f, 0.f, 0.f};
      if (gn < NN) {
        v = *(const float4*)(X + (size_t)gn * K + 4 * kq);
        if (MODE != 0) {
          float di = dinv[gn];
          v.x = fmaxf(fmaf(di, v.x, bin[4 * kq + 0]), 0.f);
          v.y = fmaxf(fmaf(di, v.y, bin[4 * kq + 1]), 0.f);
          v.z = fmaxf(fmaf(di, v.z, bin[4 * kq + 2]), 0.f);
          v.w = fmaxf(fmaf(di, v.w, bin[4 * kq + 3]), 0.f);
        }
      }
      sX[n][4 * kq + 0] = v.x;
      sX[n][4 * kq + 1] = v.y;
      sX[n][4 * kq + 2] = v.z;
      sX[n][4 * kq + 3] = v.w;
    }
  }
  __syncthreads();

  const int cx = tid % TCX, ry = tid / TCX;
  const int c0 = cx * CPT, r0 = ry * NPT;
  float acc[NPT][CPT] = {};
  #pragma unroll 4
  for (int k = 0; k < K; ++k) {
    float wv[CPT], xv[NPT];
    #pragma unroll
    for (int j = 0; j < CPT; ++j) wv[j] = sW[k * M + c0 + j];
    #pragma unroll
    for (int i = 0; i < NPT; ++i) xv[i] = sX[r0 + i][k];
    #pragma unroll
    for (int i = 0; i < NPT; ++i)
      #pragma unroll
      for (int j = 0; j < CPT; ++j) acc[i][j] = fmaf(xv[i], wv[j], acc[i][j]);
  }

  #pragma unroll
  for (int i = 0; i < NPT; ++i) {
    int gn = nb + r0 + i;
    if (gn >= NN) continue;
    if (MODE == 2) {
      #pragma unroll
      for (int j = 0; j < CPT; ++j)
        outA[(size_t)gn * M + c0 + j] = acc[i][j] + bout[c0 + j];
    } else {
      float di = dinv[gn];
      #pragma unroll
      for (int j = 0; j < CPT; ++j)
        outA[(size_t)gn * M + c0 + j] = acc[i][j] * di;
    }
  }
}

extern "C" void kernel_launch(void* const* d_in, const int* in_sizes, int n_in,
                              void* d_out, int out_size, void* d_ws,
                              size_t ws_size, hipStream_t stream) {
  const float* x   = (const float*)d_in[0];
  const int*   ei  = (const int*)d_in[1];
  const float* W1  = (const float*)d_in[2];
  const float* b1  = (const float*)d_in[3];
  const float* W2  = (const float*)d_in[4];
  const float* b2  = (const float*)d_in[5];
  const float* Wfc = (const float*)d_in[6];
  const float* bfc = (const float*)d_in[7];
  float* out = (float*)d_out;

  // workspace layout (floats/ints, all 16B-aligned regions)
  float* dinv = (float*)d_ws;                     // [50048]
  float* A = dinv + 50048;                        // [N*96] hn
  float* B = A + (size_t)NN * HID_C;              // [N*96] aggregated
  int* counts    = (int*)(B + (size_t)NN * HID_C);  // [50048]
  int* row_start = counts + 50048;                  // [50048]
  int* cursor    = row_start + 50048;               // [50048]
  int* partials  = cursor + 50048;                  // [256]
  int* srcs      = partials + 256;                  // [NE]

  // --- CSR build + degrees ---
  hist_zero<<<NCHUNK, 256, 0, stream>>>(counts);
  hist<<<(NE + 255) / 256, 256, 0, stream>>>(ei, counts);
  scan_reduce<<<NCHUNK, 256, 0, stream>>>(counts, partials);
  scan_partials<<<1, 256, 0, stream>>>(partials);
  scan_finalize<<<NCHUNK, 256, 0, stream>>>(counts, partials, row_start,
                                            cursor, dinv);
  fill_csr<<<(NE + 255) / 256, 256, 0, stream>>>(ei, cursor, srcs);

  constexpr int GQ = (NN * (HID_C / 4) + 255) / 256;

  // Layer 1: A = (x @ W1) * dinv ; B = gather(A)
  gcn_gemm<64, 96, 64, 8, 6, 0, 128>
      <<<(NN + 63) / 64, 128, 0, stream>>>(x, W1, nullptr, dinv, A, nullptr);
  gather<<<GQ, 256, 0, stream>>>(row_start, counts, srcs, A, B);

  // Layer 2: A = (relu(dinv*B + b1) @ W2) * dinv ; B = gather(A)
  gcn_gemm<96, 96, 64, 8, 6, 1, 128>
      <<<(NN + 63) / 64, 128, 0, stream>>>(B, W2, b1, dinv, A, nullptr);
  gather<<<GQ, 256, 0, stream>>>(row_start, counts, srcs, A, B);

  // FC: out = relu(dinv*B + b2) @ Wfc + bfc
  gcn_gemm<96, 32, 128, 8, 4, 2, 128>
      <<<(NN + 127) / 128, 128, 0, stream>>>(B, Wfc, b2, dinv, out, bfc);
}